// Round 1
// baseline (78.621 us; speedup 1.0000x reference)
//
#include <hip/hip_runtime.h>

typedef unsigned short ushort_t;
typedef __attribute__((ext_vector_type(8))) _Float16 f16x8;
typedef __attribute__((ext_vector_type(4))) _Float16 f16x4;
typedef __attribute__((ext_vector_type(4))) float   f32x4;

#define BATCH 16384
#define NFEAT 512
#define NCLS  1000
#define NLEAF 256
#define NINT  255
#define NPAD  1024   // padded class dim for GEMM2

__device__ __forceinline__ void gload16(const void* g, void* l) {
  __builtin_amdgcn_global_load_lds(
      (const __attribute__((address_space(1))) void*)g,
      (__attribute__((address_space(3))) void*)l, 16, 0, 0);
}

// ---- convert x (f32 -> f16), vectorized float4 -> f16x4 ----
__global__ __launch_bounds__(256) void cvt_x(const float4* __restrict__ in,
                                             f16x4* __restrict__ out) {
  int i = blockIdx.x * 256 + threadIdx.x;
  float4 v = in[i];
  f16x4 o;
  o[0] = (_Float16)v.x; o[1] = (_Float16)v.y;
  o[2] = (_Float16)v.z; o[3] = (_Float16)v.w;
  out[i] = o;
}

// ---- convert gate_w (255x512) -> f16 padded to 256x512 (row 255 = 0) ----
__global__ __launch_bounds__(256) void cvt_gw(const float4* __restrict__ in,
                                              f16x4* __restrict__ out) {
  int i = blockIdx.x * 256 + threadIdx.x;   // quad index, 32768 total
  int row = i >> 7;                          // 128 quads per row
  f16x4 o;
  if (row < NINT) {
    float4 v = in[i];
    o[0] = (_Float16)v.x; o[1] = (_Float16)v.y;
    o[2] = (_Float16)v.z; o[3] = (_Float16)v.w;
  } else {
    o[0] = o[1] = o[2] = o[3] = (_Float16)0.f;
  }
  out[i] = o;
}

// ---- softmax rows of leaf_logits (256x1000) -> distT[c][l] f16, rows>=1000 zeroed ----
__global__ __launch_bounds__(256) void softmax_t(const float* __restrict__ L,
                                                 _Float16* __restrict__ distT) {
  __shared__ float red[256];
  int l = blockIdx.x, t = threadIdx.x;
  float v[4];
  float mx = -1e30f;
#pragma unroll
  for (int i = 0; i < 4; ++i) {
    int c = t + i * 256;
    if (c < NCLS) { v[i] = L[l * NCLS + c]; mx = fmaxf(mx, v[i]); }
    else v[i] = -1e30f;
  }
  red[t] = mx; __syncthreads();
  for (int s = 128; s > 0; s >>= 1) {
    if (t < s) red[t] = fmaxf(red[t], red[t + s]);
    __syncthreads();
  }
  mx = red[0]; __syncthreads();
  float e[4], sum = 0.f;
#pragma unroll
  for (int i = 0; i < 4; ++i) {
    int c = t + i * 256;
    if (c < NCLS) { e[i] = expf(v[i] - mx); sum += e[i]; } else e[i] = 0.f;
  }
  red[t] = sum; __syncthreads();
  for (int s = 128; s > 0; s >>= 1) {
    if (t < s) red[t] += red[t + s];
    __syncthreads();
  }
  float inv = 1.f / red[0];
#pragma unroll
  for (int i = 0; i < 4; ++i) {
    int c = t + i * 256;
    if (c < NCLS) distT[(size_t)c * NLEAF + l] = (_Float16)(e[i] * inv);
  }
  if (t < NPAD - NCLS) distT[(size_t)(NCLS + t) * NLEAF + l] = (_Float16)0.f;
}

// ---- mu: per batch row, product over tree path -> f16 ----
__global__ __launch_bounds__(256) void mu_kernel(const float* __restrict__ P,
                                                 _Float16* __restrict__ mu) {
  __shared__ float p[256];
  int r = blockIdx.x, t = threadIdx.x;
  p[t] = P[(size_t)r * 256 + t];
  __syncthreads();
  float m = 1.f;
  int l = t;
#pragma unroll
  for (int d = 0; d < 8; ++d) {
    int node = (1 << d) - 1 + (l >> (8 - d));
    int bit  = (l >> (7 - d)) & 1;
    float g = p[node];
    m *= bit ? g : (1.f - g);
  }
  mu[(size_t)r * 256 + t] = (_Float16)m;
}

// ---- gemm_bt: C = A(MxK) * B^T(NxK), f16 MFMA 16x16x32, 128x128 tile, BK=64 ----
// EPI 0: out = sigmoid(acc + bias[col]) -> P (f32, ldo=256)
// EPI 1: out[row*ldo+col] = acc if col < ncol
template <int EPI>
__global__ __launch_bounds__(256)
void gemm_bt(const _Float16* __restrict__ A, const _Float16* __restrict__ B,
             const float* __restrict__ bias, float* __restrict__ out,
             int K, int ldo, int ncol) {
  __shared__ _Float16 lA[128 * 64];
  __shared__ _Float16 lB[128 * 64];
  const int tid  = threadIdx.x;
  const int wave = tid >> 6, lane = tid & 63;
  const int ln15 = lane & 15, lhi = lane >> 4;
  const int wr = wave >> 1, wc = wave & 1;
  const int r0 = blockIdx.x * 128;
  const int c0 = blockIdx.y * 128;

  f32x4 acc[4][4] = {};

  const _Float16* gA = A + (size_t)r0 * K;
  const _Float16* gB = B + (size_t)c0 * K;

  for (int k0 = 0; k0 < K; k0 += 64) {
    // stage A,B tiles: 16 KB each, 16 chunks of 1024B, 4 per wave
#pragma unroll
    for (int i = 0; i < 4; ++i) {
      int chunk = (i * 4 + wave) * 1024;      // byte offset in tile
      int e = (chunk >> 1) + lane * 8;        // element offset
      int r = e >> 6, c = e & 63;
      gload16(gA + (size_t)r * K + k0 + c, (char*)lA + chunk);
      gload16(gB + (size_t)r * K + k0 + c, (char*)lB + chunk);
    }
    __syncthreads();
#pragma unroll
    for (int kk = 0; kk < 2; ++kk) {
      f16x8 a[4], b[4];
#pragma unroll
      for (int m = 0; m < 4; ++m)
        a[m] = *(const f16x8*)&lA[(wr * 64 + m * 16 + ln15) * 64 + kk * 32 + lhi * 8];
#pragma unroll
      for (int n = 0; n < 4; ++n)
        b[n] = *(const f16x8*)&lB[(wc * 64 + n * 16 + ln15) * 64 + kk * 32 + lhi * 8];
#pragma unroll
      for (int m = 0; m < 4; ++m)
#pragma unroll
        for (int n = 0; n < 4; ++n)
          acc[m][n] = __builtin_amdgcn_mfma_f32_16x16x32_f16(a[m], b[n], acc[m][n], 0, 0, 0);
    }
    __syncthreads();
  }

#pragma unroll
  for (int m = 0; m < 4; ++m) {
#pragma unroll
    for (int n = 0; n < 4; ++n) {
      int col = c0 + wc * 64 + n * 16 + ln15;
#pragma unroll
      for (int j = 0; j < 4; ++j) {
        int row = r0 + wr * 64 + m * 16 + lhi * 4 + j;
        float v = acc[m][n][j];
        if (EPI == 0) {
          float bb = (col < NINT) ? bias[col] : 0.f;
          v = 1.f / (1.f + __expf(-(v + bb)));
          out[(size_t)row * ldo + col] = v;
        } else {
          if (col < ncol) out[(size_t)row * ldo + col] = v;
        }
      }
    }
  }
}

extern "C" void kernel_launch(void* const* d_in, const int* in_sizes, int n_in,
                              void* d_out, int out_size, void* d_ws, size_t ws_size,
                              hipStream_t stream) {
  const float* x  = (const float*)d_in[0];   // 16384x512
  const float* gw = (const float*)d_in[1];   // 255x512
  const float* gb = (const float*)d_in[2];   // 255
  const float* ll = (const float*)d_in[3];   // 256x1000
  float* out = (float*)d_out;                // 16384x1000
  char* ws = (char*)d_ws;

  // ws layout (bytes)
  _Float16* xh    = (_Float16*)(ws);                         // 16,777,216
  _Float16* gwh   = (_Float16*)(ws + 16777216);              //    262,144
  _Float16* distT = (_Float16*)(ws + 16777216 + 262144);     //    524,288
  float*    P     = (float*)   (ws + 17563648);              // 16,777,216
  _Float16* mu    = (_Float16*)(ws + 34340864);              //  8,388,608
  // total 42,729,472 bytes

  cvt_x   <<<8192, 256, 0, stream>>>((const float4*)x,  (f16x4*)xh);
  cvt_gw  <<<128,  256, 0, stream>>>((const float4*)gw, (f16x4*)gwh);
  softmax_t<<<256, 256, 0, stream>>>(ll, distT);
  gemm_bt<0><<<dim3(BATCH / 128, 2), 256, 0, stream>>>(xh, gwh, gb, P, NFEAT, 256, 256);
  mu_kernel<<<BATCH, 256, 0, stream>>>(P, mu);
  gemm_bt<1><<<dim3(BATCH / 128, NPAD / 128), 256, 0, stream>>>(mu, distT, nullptr, out, NLEAF, NCLS, NCLS);
}